// Round 1
// baseline (377.233 us; speedup 1.0000x reference)
//
#include <hip/hip_runtime.h>
#include <hip/hip_bf16.h>
#include <math.h>

// Problem dims (QwenStyleSparseMoEBlock): T=4096 tokens, D=1024, F=2048, E=4, top-2.
// Inputs (fp32): x[2,2048,1024], w_gate[4,1024], w_gate_proj[4,1024,2048],
//                w_up_proj[4,1024,2048], w_down_proj[4,2048,1024]
// Output (fp32): [2,2048,1024]
//
// Pipeline: routing -> bf16 convert/transpose pre-pass -> per-expert fused
// GEMM1 (gate&up + exact GELU) -> GEMM2 (+cw-weighted accumulate into d_out).
// ws usage: 75,563,008 bytes.

typedef float  f32x4 __attribute__((ext_vector_type(4)));
typedef short  s16x8 __attribute__((ext_vector_type(8)));

__device__ __forceinline__ unsigned short f2bf(float f) {
  union { float f; unsigned int u; } v; v.f = f;
  return (unsigned short)((v.u + 0x7fffu + ((v.u >> 16) & 1u)) >> 16);  // RNE
}

__device__ __forceinline__ void glds16(const void* g, void* l) {
  __builtin_amdgcn_global_load_lds(
      (const __attribute__((address_space(1))) void*)g,
      (__attribute__((address_space(3))) void*)l, 16, 0, 0);
}

// ---------------- routing: cw[t][e] = normalized top-2 softmax weight ----------------
__global__ void k_routing(const float* __restrict__ x, const float* __restrict__ wg,
                          float* __restrict__ cw) {
  const int lane = threadIdx.x & 63;
  const int tok  = blockIdx.x * 4 + (threadIdx.x >> 6);
  const float* xr = x + (size_t)tok * 1024;
  float a0 = 0.f, a1 = 0.f, a2 = 0.f, a3 = 0.f;
#pragma unroll
  for (int j = 0; j < 16; ++j) {
    const int d = j * 64 + lane;
    const float xv = xr[d];
    a0 += xv * wg[0 * 1024 + d];
    a1 += xv * wg[1 * 1024 + d];
    a2 += xv * wg[2 * 1024 + d];
    a3 += xv * wg[3 * 1024 + d];
  }
#pragma unroll
  for (int off = 32; off; off >>= 1) {
    a0 += __shfl_xor(a0, off);
    a1 += __shfl_xor(a1, off);
    a2 += __shfl_xor(a2, off);
    a3 += __shfl_xor(a3, off);
  }
  if (lane == 0) {
    float l[4] = {a0, a1, a2, a3};
    const float m = fmaxf(fmaxf(l[0], l[1]), fmaxf(l[2], l[3]));
    float p[4];
#pragma unroll
    for (int e = 0; e < 4; ++e) p[e] = expf(l[e] - m);
    int i1 = 0; float b1 = p[0];
#pragma unroll
    for (int e = 1; e < 4; ++e) if (p[e] > b1) { b1 = p[e]; i1 = e; }
    int i2 = -1; float b2 = -1.f;
#pragma unroll
    for (int e = 0; e < 4; ++e) if (e != i1 && p[e] > b2) { b2 = p[e]; i2 = e; }
    const float inv = 1.f / (b1 + b2);
    float o[4] = {0.f, 0.f, 0.f, 0.f};
    o[i1] = b1 * inv; o[i2] = b2 * inv;
    float4* dst = (float4*)(cw + (size_t)tok * 4);
    *dst = make_float4(o[0], o[1], o[2], o[3]);
  }
}

// ---------------- X fp32 -> bf16 (layout preserved) ----------------
__global__ void k_cvt_x(const float* __restrict__ in, unsigned short* __restrict__ out) {
  const int i = blockIdx.x * blockDim.x + threadIdx.x;  // 1,048,576 threads, 4 elems each
  const float4 v = ((const float4*)in)[i];
  ushort4 o;
  o.x = f2bf(v.x); o.y = f2bf(v.y); o.z = f2bf(v.z); o.w = f2bf(v.w);
  ((ushort4*)out)[i] = o;
}

// ---------------- W [R][C] fp32 -> Wt [C][R] bf16 (per expert via blockIdx.z) ----------------
__global__ void k_tcvt(const float* __restrict__ in, unsigned short* __restrict__ out,
                       const int R, const int C) {
  __shared__ float t[32][33];
  const size_t off = (size_t)blockIdx.z * R * C;
  in += off; out += off;
  const int c0 = blockIdx.x * 32, r0 = blockIdx.y * 32;
  const int tx = threadIdx.x, ty = threadIdx.y;  // 32 x 8
#pragma unroll
  for (int i = 0; i < 4; ++i)
    t[ty + 8 * i][tx] = in[(size_t)(r0 + ty + 8 * i) * C + c0 + tx];
  __syncthreads();
#pragma unroll
  for (int i = 0; i < 4; ++i)
    out[(size_t)(c0 + ty + 8 * i) * R + r0 + tx] = f2bf(t[tx][ty + 8 * i]);
}

// ---------------- GEMM1: H = gelu(X@Wg) * (X@Wu), bf16 out ----------------
// X: [4096][1024] bf16, Wgt/Wut: [2048][1024] bf16 ([N][K]), H: [4096][2048] bf16
__global__ __launch_bounds__(256, 2)
void k_gemm1(const unsigned short* __restrict__ Xb,
             const unsigned short* __restrict__ Wgt,
             const unsigned short* __restrict__ Wut,
             unsigned short* __restrict__ H) {
  __shared__ __align__(16) unsigned short sA[128 * 64];
  __shared__ __align__(16) unsigned short sG[128 * 64];
  __shared__ __align__(16) unsigned short sU[128 * 64];
  const int tid = threadIdx.x;
  const int lane = tid & 63, wid = tid >> 6;
  const int wm = wid >> 1, wn = wid & 1;
  const int bm = blockIdx.x, bn = blockIdx.y;

  f32x4 accg[4][4] = {};
  f32x4 accu[4][4] = {};

  const int srow = lane >> 3;         // row within 8-row chunk
  const int scol = (lane & 7) * 8;    // bf16 col within 64
  const size_t abase = (size_t)(bm * 128) * 1024;
  const size_t bbase = (size_t)(bn * 128) * 1024;

  for (int kt = 0; kt < 16; ++kt) {
    const int k0 = kt * 64;
#pragma unroll
    for (int i = 0; i < 4; ++i) {
      const int c = wid * 4 + i;          // 16 chunks of 8 rows
      const int row = c * 8 + srow;
      glds16(Xb  + abase + (size_t)row * 1024 + k0 + scol, &sA[c * 512]);
      glds16(Wgt + bbase + (size_t)row * 1024 + k0 + scol, &sG[c * 512]);
      glds16(Wut + bbase + (size_t)row * 1024 + k0 + scol, &sU[c * 512]);
    }
    __syncthreads();
#pragma unroll
    for (int ks = 0; ks < 2; ++ks) {
      const int ko = ks * 32 + (lane >> 4) * 8;
      s16x8 a[4], bg[4], bu[4];
#pragma unroll
      for (int mi = 0; mi < 4; ++mi)
        a[mi] = *(const s16x8*)&sA[(wm * 64 + mi * 16 + (lane & 15)) * 64 + ko];
#pragma unroll
      for (int ni = 0; ni < 4; ++ni) {
        bg[ni] = *(const s16x8*)&sG[(wn * 64 + ni * 16 + (lane & 15)) * 64 + ko];
        bu[ni] = *(const s16x8*)&sU[(wn * 64 + ni * 16 + (lane & 15)) * 64 + ko];
      }
#pragma unroll
      for (int mi = 0; mi < 4; ++mi)
#pragma unroll
        for (int ni = 0; ni < 4; ++ni) {
          accg[mi][ni] = __builtin_amdgcn_mfma_f32_16x16x32_bf16(a[mi], bg[ni], accg[mi][ni], 0, 0, 0);
          accu[mi][ni] = __builtin_amdgcn_mfma_f32_16x16x32_bf16(a[mi], bu[ni], accu[mi][ni], 0, 0, 0);
        }
    }
    __syncthreads();
  }
  const int r0 = bm * 128 + wm * 64;
  const int c0 = bn * 128 + wn * 64;
#pragma unroll
  for (int mi = 0; mi < 4; ++mi)
#pragma unroll
    for (int ni = 0; ni < 4; ++ni)
#pragma unroll
      for (int r = 0; r < 4; ++r) {
        const int row = r0 + mi * 16 + (lane >> 4) * 4 + r;
        const int col = c0 + ni * 16 + (lane & 15);
        const float g = accg[mi][ni][r];
        const float u = accu[mi][ni][r];
        const float h = 0.5f * g * (1.0f + erff(g * 0.70710678118654752f)) * u;
        H[(size_t)row * 2048 + col] = f2bf(h);
      }
}

// ---------------- GEMM2: out[t][d] (+)= cw[t][e] * (H @ Wd) ----------------
// H: [4096][2048] bf16, Wdt: [1024][2048] bf16 ([N][K]), out: [4096][1024] fp32
__global__ __launch_bounds__(256, 2)
void k_gemm2(const unsigned short* __restrict__ H,
             const unsigned short* __restrict__ Wdt,
             const float* __restrict__ cw,
             float* __restrict__ out, const int e) {
  __shared__ __align__(16) unsigned short sA[128 * 64];
  __shared__ __align__(16) unsigned short sB[64 * 64];
  const int tid = threadIdx.x;
  const int lane = tid & 63, wid = tid >> 6;
  const int wm = wid >> 1, wn = wid & 1;
  const int bm = blockIdx.x, bn = blockIdx.y;

  f32x4 acc[4][2] = {};
  const int srow = lane >> 3;
  const int scol = (lane & 7) * 8;

  for (int kt = 0; kt < 32; ++kt) {
    const int k0 = kt * 64;
#pragma unroll
    for (int i = 0; i < 4; ++i) {
      const int c = wid * 4 + i;
      const int row = c * 8 + srow;
      glds16(H + (size_t)(bm * 128 + row) * 2048 + k0 + scol, &sA[c * 512]);
    }
#pragma unroll
    for (int i = 0; i < 2; ++i) {
      const int c = wid * 2 + i;
      const int row = c * 8 + srow;
      glds16(Wdt + (size_t)(bn * 64 + row) * 2048 + k0 + scol, &sB[c * 512]);
    }
    __syncthreads();
#pragma unroll
    for (int ks = 0; ks < 2; ++ks) {
      const int ko = ks * 32 + (lane >> 4) * 8;
      s16x8 a[4], b[2];
#pragma unroll
      for (int mi = 0; mi < 4; ++mi)
        a[mi] = *(const s16x8*)&sA[(wm * 64 + mi * 16 + (lane & 15)) * 64 + ko];
#pragma unroll
      for (int ni = 0; ni < 2; ++ni)
        b[ni] = *(const s16x8*)&sB[(wn * 32 + ni * 16 + (lane & 15)) * 64 + ko];
#pragma unroll
      for (int mi = 0; mi < 4; ++mi)
#pragma unroll
        for (int ni = 0; ni < 2; ++ni)
          acc[mi][ni] = __builtin_amdgcn_mfma_f32_16x16x32_bf16(a[mi], b[ni], acc[mi][ni], 0, 0, 0);
    }
    __syncthreads();
  }
  const int r0 = bm * 128 + wm * 64;
  const int c0 = bn * 64 + wn * 32;
#pragma unroll
  for (int mi = 0; mi < 4; ++mi)
#pragma unroll
    for (int ni = 0; ni < 2; ++ni)
#pragma unroll
      for (int r = 0; r < 4; ++r) {
        const int row = r0 + mi * 16 + (lane >> 4) * 4 + r;
        const int col = c0 + ni * 16 + (lane & 15);
        const float w = cw[(size_t)row * 4 + e];
        const size_t oi = (size_t)row * 1024 + col;
        float v = acc[mi][ni][r] * w;
        if (e) v += out[oi];
        out[oi] = v;
      }
}

extern "C" void kernel_launch(void* const* d_in, const int* in_sizes, int n_in,
                              void* d_out, int out_size, void* d_ws, size_t ws_size,
                              hipStream_t stream) {
  const float* x     = (const float*)d_in[0];
  const float* wgate = (const float*)d_in[1];
  const float* wgp   = (const float*)d_in[2];
  const float* wup   = (const float*)d_in[3];
  const float* wdp   = (const float*)d_in[4];
  float* out = (float*)d_out;

  char* ws = (char*)d_ws;
  float* cw           = (float*)ws;                      // 4096*4*4      = 64 KB
  unsigned short* Xb  = (unsigned short*)(ws + 65536);   // 4096*1024*2   = 8 MB
  unsigned short* Wgt = Xb  + (size_t)4096 * 1024;       // 4*2048*1024*2 = 16 MB
  unsigned short* Wut = Wgt + (size_t)4 * 2048 * 1024;
  unsigned short* Wdt = Wut + (size_t)4 * 2048 * 1024;
  unsigned short* H   = Wdt + (size_t)4 * 1024 * 2048;   // 4096*2048*2   = 16 MB
  // total: 75,563,008 bytes of ws

  k_routing<<<1024, 256, 0, stream>>>(x, wgate, cw);
  k_cvt_x<<<4096, 256, 0, stream>>>(x, Xb);
  dim3 tb(32, 8);
  k_tcvt<<<dim3(64, 32, 4), tb, 0, stream>>>(wgp, Wgt, 1024, 2048);
  k_tcvt<<<dim3(64, 32, 4), tb, 0, stream>>>(wup, Wut, 1024, 2048);
  k_tcvt<<<dim3(32, 64, 4), tb, 0, stream>>>(wdp, Wdt, 2048, 1024);

  for (int e = 0; e < 4; ++e) {
    k_gemm1<<<dim3(32, 16), 256, 0, stream>>>(
        Xb, Wgt + (size_t)e * 2048 * 1024, Wut + (size_t)e * 2048 * 1024, H);
    k_gemm2<<<dim3(32, 16), 256, 0, stream>>>(
        H, Wdt + (size_t)e * 1024 * 2048, cw, out, e);
  }
}